// Round 18
// baseline (367.532 us; speedup 1.0000x reference)
//
#include <hip/hip_runtime.h>
#include <hip/hip_bf16.h>
#include <math.h>

#define B_   64
#define N_   2048
#define E_   32768
#define K_   1024
#define F_   128
#define C_   384
#define NB_  (B_ * N_)

typedef __bf16 bf16x8 __attribute__((ext_vector_type(8)));
typedef float  f32x4  __attribute__((ext_vector_type(4)));
typedef float  f32x2  __attribute__((ext_vector_type(2)));

__device__ __forceinline__ float bf2f(unsigned int u) {
  return __uint_as_float(u << 16);   // uses low 16 bits
}
__device__ __forceinline__ unsigned int f2bf(float f) {
  unsigned int x = __float_as_uint(f);
  return (x + 0x7fffu + ((x >> 16) & 1u)) >> 16;   // RNE
}
__device__ __forceinline__ f32x2 bf2x(unsigned int u) {
  f32x2 r;
  r.x = __uint_as_float(u << 16);
  r.y = __uint_as_float(u & 0xffff0000u);
  return r;
}
// LDS staging index: row-major [rows][128] shorts, XOR swizzle at 8-short granules.
__device__ __forceinline__ int swz(int row, int scol) {
  return (row * F_ + scol) ^ ((row & 7) << 3);
}

// ---------------- graph prep: 4 blocks per graph, XCD-pinned (share one L2) ----------------
__global__ __launch_bounds__(1024) void k_prep(const int* __restrict__ src,
                                               const int* __restrict__ dst,
                                               float* __restrict__ norm_s,
                                               float* __restrict__ norm_d,
                                               int* __restrict__ row_ptr,
                                               int* __restrict__ csr) {
  __shared__ int h_in[512];
  __shared__ int h_out[512];
  __shared__ int rowst[512];
  __shared__ int part[512];
  __shared__ int rtot[4];
  int blk = blockIdx.x;
  int b = ((blk >> 5) << 3) | (blk & 7);
  int r = (blk >> 3) & 3;
  int lo = r << 9;
  int t = threadIdx.x;
  if (t < 512) { h_in[t] = 0; h_out[t] = 0; }
  if (t < 4) rtot[t] = 0;
  __syncthreads();
  const int4* sp4 = (const int4*)(src + (size_t)b * E_);
  const int4* dp4 = (const int4*)(dst + (size_t)b * E_);
  int c0 = 0, c1 = 0, c2 = 0, c3 = 0;
  for (int i = t; i < E_ / 4; i += 2048) {
    int4 sA = sp4[i], dA = dp4[i];
    int4 sB = sp4[i + 1024], dB = dp4[i + 1024];
#define EDGE(ss, dd) { int dr = (dd) >> 9; \
    c0 += (dr == 0); c1 += (dr == 1); c2 += (dr == 2); c3 += (dr == 3); \
    if (dr == r) atomicAdd(&h_in[(dd) - lo], 1); \
    if (((ss) >> 9) == r) atomicAdd(&h_out[(ss) - lo], 1); }
    EDGE(sA.x, dA.x); EDGE(sA.y, dA.y); EDGE(sA.z, dA.z); EDGE(sA.w, dA.w);
    EDGE(sB.x, dB.x); EDGE(sB.y, dB.y); EDGE(sB.z, dB.z); EDGE(sB.w, dB.w);
#undef EDGE
  }
  if (c0) atomicAdd(&rtot[0], c0);
  if (c1) atomicAdd(&rtot[1], c1);
  if (c2) atomicAdd(&rtot[2], c2);
  if (c3) atomicAdd(&rtot[3], c3);
  __syncthreads();
  if (t < 512) {
    int dv = h_out[t], di = h_in[t];
    norm_s[b * N_ + lo + t] = dv > 0 ? rsqrtf((float)dv) : 0.f;
    norm_d[b * N_ + lo + t] = di > 0 ? rsqrtf((float)di) : 0.f;
  }
  int base = 0;
  if (r > 0) base += rtot[0];
  if (r > 1) base += rtot[1];
  if (r > 2) base += rtot[2];
  if (t < 512) part[t] = h_in[t];
  __syncthreads();
  for (int off = 1; off < 512; off <<= 1) {
    int x = (t >= off && t < 512) ? part[t - off] : 0;
    __syncthreads();
    if (t < 512) part[t] += x;
    __syncthreads();
  }
  if (t < 512) {
    int st = base + part[t] - h_in[t];
    rowst[t] = st;
    row_ptr[b * (N_ + 1) + lo + t] = st;
    h_in[t] = 0;
  }
  if (r == 3 && t == 511) row_ptr[b * (N_ + 1) + N_] = base + part[511];
  __syncthreads();
  int* cg = csr + (size_t)b * E_;
  for (int i = t; i < E_ / 4; i += 2048) {
    int4 sA = sp4[i], dA = dp4[i];
    int4 sB = sp4[i + 1024], dB = dp4[i + 1024];
#define FILL(ss, dd) if (((dd) >> 9) == r) { \
    int pos = rowst[(dd) - lo] + atomicAdd(&h_in[(dd) - lo], 1); cg[pos] = (ss); }
    FILL(sA.x, dA.x); FILL(sA.y, dA.y); FILL(sA.z, dA.z); FILL(sA.w, dA.w);
    FILL(sB.x, dB.x); FILL(sB.y, dB.y); FILL(sB.z, dB.z); FILL(sB.w, dB.w);
#undef FILL
  }
}

// ---------------- per-graph counting sort of nodes by in-degree (descending) ----------------
__global__ __launch_bounds__(256) void k_sort(const int* __restrict__ row_ptr,
                                              int* __restrict__ order) {
  __shared__ int hist[64];
  __shared__ int base[64];
  int b = blockIdx.x, t = threadIdx.x;
  if (t < 64) hist[t] = 0;
  __syncthreads();
  int degs[8];
  const int* rp = row_ptr + b * (N_ + 1);
  for (int j = 0; j < 8; j++) {
    int n = t * 8 + j;
    int d = rp[n + 1] - rp[n];
    degs[j] = d;
    int bin = 63 - min(d, 63);
    atomicAdd(&hist[bin], 1);
  }
  __syncthreads();
  if (t == 0) {
    int run = 0;
    for (int i = 0; i < 64; i++) { base[i] = run; run += hist[i]; hist[i] = 0; }
  }
  __syncthreads();
  for (int j = 0; j < 8; j++) {
    int n = t * 8 + j;
    int bin = 63 - min(degs[j], 63);
    int pos = base[bin] + atomicAdd(&hist[bin], 1);
    order[b * N_ + pos] = n;
  }
}

// ---------------- feat f32 -> bf16 pre-scaled by norm_s (XCD-pinned per graph) ----------------
__global__ __launch_bounds__(256) void k_f2bf_scaled(const float* __restrict__ in,
                                                     const float* __restrict__ norm_s,
                                                     unsigned short* __restrict__ out) {
  int blk = blockIdx.x;
  int b = ((blk >> 10) << 3) | (blk & 7);
  int nb = (blk >> 3) & 127;
  int t = threadIdx.x;
  int node = b * N_ + nb * 16 + (t >> 4);
  int f0 = (t & 15) * 8;
  float ns = norm_s[node];
  const float4* p = (const float4*)(in + (size_t)node * F_ + f0);
  float4 v0 = p[0], v1 = p[1];
  uint4 o;
  o.x = f2bf(v0.x * ns) | (f2bf(v0.y * ns) << 16);
  o.y = f2bf(v0.z * ns) | (f2bf(v0.w * ns) << 16);
  o.z = f2bf(v1.x * ns) | (f2bf(v1.y * ns) << 16);
  o.w = f2bf(v1.z * ns) | (f2bf(v1.w * ns) << 16);
  *(uint4*)(out + (size_t)node * F_ + f0) = o;
}

// ---------------- aggregate: 16 lanes/node, 16 nodes/block, degree-sorted node order ----------------
__global__ __launch_bounds__(256) void k_agg(const unsigned short* __restrict__ hs,
                                             const int* __restrict__ row_ptr,
                                             const int* __restrict__ csr,
                                             const float* __restrict__ norm_d,
                                             const int* __restrict__ order,
                                             unsigned short* __restrict__ agg) {
  int blk = blockIdx.x;
  int b = ((blk >> 10) << 3) | (blk & 7);
  int nb = (blk >> 3) & 127;
  int t = threadIdx.x;
  int nl = t >> 4, f8 = t & 15;
  int n = order[b * N_ + nb * 16 + nl];
  int node = b * N_ + n;
  int r0 = row_ptr[b * (N_ + 1) + n], r1 = row_ptr[b * (N_ + 1) + n + 1];
  const int* cs = csr + (size_t)b * E_;
  const unsigned short* hb = hs + ((size_t)b * N_) * F_ + f8 * 8;
  f32x2 a01 = {0.f, 0.f}, a23 = {0.f, 0.f}, a45 = {0.f, 0.f}, a67 = {0.f, 0.f};
#define ACC8(u) { a01 += bf2x(u.x); a23 += bf2x(u.y); a45 += bf2x(u.z); a67 += bf2x(u.w); }
  int e = r0;
  for (; e + 8 <= r1; e += 8) {
    int s0 = cs[e],     s1 = cs[e + 1], s2 = cs[e + 2], s3 = cs[e + 3];
    int s4 = cs[e + 4], s5 = cs[e + 5], s6 = cs[e + 6], s7 = cs[e + 7];
    uint4 u0 = *(const uint4*)(hb + (size_t)s0 * F_);
    uint4 u1 = *(const uint4*)(hb + (size_t)s1 * F_);
    uint4 u2 = *(const uint4*)(hb + (size_t)s2 * F_);
    uint4 u3 = *(const uint4*)(hb + (size_t)s3 * F_);
    uint4 u4 = *(const uint4*)(hb + (size_t)s4 * F_);
    uint4 u5 = *(const uint4*)(hb + (size_t)s5 * F_);
    uint4 u6 = *(const uint4*)(hb + (size_t)s6 * F_);
    uint4 u7 = *(const uint4*)(hb + (size_t)s7 * F_);
    ACC8(u0); ACC8(u1); ACC8(u2); ACC8(u3);
    ACC8(u4); ACC8(u5); ACC8(u6); ACC8(u7);
  }
  for (; e < r1; ++e) {
    int s0 = cs[e];
    uint4 u0 = *(const uint4*)(hb + (size_t)s0 * F_);
    ACC8(u0);
  }
#undef ACC8
  float wd = norm_d[node];
  uint4 o;
  o.x = f2bf(a01.x * wd) | (f2bf(a01.y * wd) << 16);
  o.y = f2bf(a23.x * wd) | (f2bf(a23.y * wd) << 16);
  o.z = f2bf(a45.x * wd) | (f2bf(a45.y * wd) << 16);
  o.w = f2bf(a67.x * wd) | (f2bf(a67.y * wd) << 16);
  *(uint4*)(agg + (size_t)node * F_ + f8 * 8) = o;
}

// ---------------- pack W (f32 [128k][128n]) into MFMA fragment layout, bf16 hi/lo ----------------
__global__ __launch_bounds__(256) void k_packW(const float* __restrict__ W,
                                               unsigned short* __restrict__ wp_hi,
                                               unsigned short* __restrict__ wp_lo) {
  int tid = blockIdx.x * 256 + threadIdx.x;
  int lane = tid & 63, frag = tid >> 6;
  if (frag >= 32) return;
  int kt = frag >> 3, nt = frag & 7;
  int k0 = kt * 32 + (lane >> 4) * 8;
  int n = nt * 16 + (lane & 15);
  for (int j = 0; j < 8; j++) {
    float w = W[(size_t)(k0 + j) * 128 + n];
    unsigned int hi = f2bf(w);
    float whi = bf2f(hi);
    unsigned int lo = f2bf(w - whi);
    wp_hi[(size_t)tid * 8 + j] = (unsigned short)hi;
    wp_lo[(size_t)tid * 8 + j] = (unsigned short)lo;
  }
}

// ---------------- MFMA GEMM (transposed) + LDS-staged coalesced epilogue + fused score-y ----------------
// 128 threads (2 waves), 64 nodes/block, grid 2048, XCD-pinned:
// blockIdx = (b>>3)*256 + nb*8 + (b&7), nb in [0,32).
// hs is computed from the staged cr values during read-back (one extra bf16 rounding).
template <bool WRITE_HS>
__global__ __launch_bounds__(128) void k_gemm_mfma(const unsigned short* __restrict__ agg,
                                                   const unsigned short* __restrict__ wp_hi,
                                                   const unsigned short* __restrict__ wp_lo,
                                                   const float* __restrict__ bias,
                                                   unsigned short* __restrict__ cr,
                                                   int out_off,
                                                   const float* __restrict__ norm_s,
                                                   unsigned short* __restrict__ hs,
                                                   const float* __restrict__ Wsc,
                                                   float* __restrict__ ybuf,
                                                   int ymode) {
  __shared__ unsigned short Stg[64 * F_];        // 16 KB staging
  int blk = blockIdx.x;
  int b = ((blk >> 8) << 3) | (blk & 7);
  int nb = (blk >> 3) & 31;
  int t = threadIdx.x;
  int wave = t >> 6, lane = t & 63;
  int gbase = b * N_ + nb * 64;
  int rl0 = wave * 32;
  int arow = lane & 15, kg = lane >> 4;

  f32x4 acc[2][8];
#pragma unroll
  for (int i = 0; i < 2; i++)
#pragma unroll
    for (int j = 0; j < 8; j++) acc[i][j] = (f32x4){0.f, 0.f, 0.f, 0.f};

#pragma unroll
  for (int kt = 0; kt < 4; ++kt) {
    bf16x8 a0 = *(const bf16x8*)(agg + (size_t)(gbase + rl0 + arow) * F_ + kt * 32 + kg * 8);
    bf16x8 a1 = *(const bf16x8*)(agg + (size_t)(gbase + rl0 + 16 + arow) * F_ + kt * 32 + kg * 8);
    const unsigned short* bh = wp_hi + ((size_t)(kt * 8) * 64 + lane) * 8;
    const unsigned short* bl = wp_lo + ((size_t)(kt * 8) * 64 + lane) * 8;
#pragma unroll
    for (int nt = 0; nt < 8; ++nt) {
      bf16x8 bhv = *(const bf16x8*)(bh + (size_t)nt * 64 * 8);
      bf16x8 blv = *(const bf16x8*)(bl + (size_t)nt * 64 * 8);
      acc[0][nt] = __builtin_amdgcn_mfma_f32_16x16x32_bf16(bhv, a0, acc[0][nt], 0, 0, 0);
      acc[0][nt] = __builtin_amdgcn_mfma_f32_16x16x32_bf16(blv, a0, acc[0][nt], 0, 0, 0);
      acc[1][nt] = __builtin_amdgcn_mfma_f32_16x16x32_bf16(bhv, a1, acc[1][nt], 0, 0, 0);
      acc[1][nt] = __builtin_amdgcn_mfma_f32_16x16x32_bf16(blv, a1, acc[1][nt], 0, 0, 0);
    }
  }

  int fb = kg * 4;
  int l0 = rl0 + arow, l1 = rl0 + 16 + arow;
  float yp0 = 0.f, yp1 = 0.f;
#pragma unroll
  for (int nt = 0; nt < 8; ++nt) {
    float4 bv = *(const float4*)(bias + nt * 16 + fb);
    acc[0][nt][0] += bv.x; acc[0][nt][1] += bv.y; acc[0][nt][2] += bv.z; acc[0][nt][3] += bv.w;
    acc[1][nt][0] += bv.x; acc[1][nt][1] += bv.y; acc[1][nt][2] += bv.z; acc[1][nt][3] += bv.w;
    uint2 p0, p1;
    p0.x = f2bf(acc[0][nt][0]) | (f2bf(acc[0][nt][1]) << 16);
    p0.y = f2bf(acc[0][nt][2]) | (f2bf(acc[0][nt][3]) << 16);
    p1.x = f2bf(acc[1][nt][0]) | (f2bf(acc[1][nt][1]) << 16);
    p1.y = f2bf(acc[1][nt][2]) | (f2bf(acc[1][nt][3]) << 16);
    *(uint2*)&Stg[swz(l0, nt * 16 + fb)] = p0;
    *(uint2*)&Stg[swz(l1, nt * 16 + fb)] = p1;
    float4 wv = *(const float4*)(Wsc + out_off + nt * 16 + fb);
    yp0 += bf2f(p0.x) * wv.x + bf2f(p0.x >> 16) * wv.y + bf2f(p0.y) * wv.z + bf2f(p0.y >> 16) * wv.w;
    yp1 += bf2f(p1.x) * wv.x + bf2f(p1.x >> 16) * wv.y + bf2f(p1.y) * wv.z + bf2f(p1.y >> 16) * wv.w;
  }
  yp0 += __shfl_xor(yp0, 16); yp0 += __shfl_xor(yp0, 32);
  yp1 += __shfl_xor(yp1, 16); yp1 += __shfl_xor(yp1, 32);
  if (kg == 0) {
    int n0 = gbase + l0, n1 = gbase + l1;
    if (ymode == 0)      { ybuf[n0] = yp0; ybuf[n1] = yp1; }
    else if (ymode == 1) { ybuf[n0] += yp0; ybuf[n1] += yp1; }
    else                 { ybuf[n0] = (ybuf[n0] + yp0) * norm_s[n0];
                           ybuf[n1] = (ybuf[n1] + yp1) * norm_s[n1]; }
  }

  // coalesced read-back: cr store + (optional) hs computed on the fly
  int rrow = lane >> 4, chunk = lane & 15;
#pragma unroll
  for (int it = 0; it < 8; ++it) {
    int rl = rl0 + it * 4 + rrow;
    uint4 vv = *(const uint4*)&Stg[swz(rl, chunk * 8)];
    *(uint4*)(cr + (size_t)(gbase + rl) * C_ + out_off + chunk * 8) = vv;
    if (WRITE_HS) {
      float ns = norm_s[gbase + rl];
      uint4 q;
      q.x = f2bf(bf2f(vv.x) * ns) | (f2bf(bf2f(vv.x >> 16) * ns) << 16);
      q.y = f2bf(bf2f(vv.y) * ns) | (f2bf(bf2f(vv.y >> 16) * ns) << 16);
      q.z = f2bf(bf2f(vv.z) * ns) | (f2bf(bf2f(vv.z >> 16) * ns) << 16);
      q.w = f2bf(bf2f(vv.w) * ns) | (f2bf(bf2f(vv.w >> 16) * ns) << 16);
      *(uint4*)(hs + (size_t)(gbase + rl) * F_ + chunk * 8) = q;
    }
  }
}

// ---------------- score stage 2: score[n] = norm_d[n] * sum_in y[src] + bs ----------------
__global__ __launch_bounds__(256) void k_score_agg(const float* __restrict__ y,
                                                   const int* __restrict__ row_ptr,
                                                   const int* __restrict__ csr,
                                                   const float* __restrict__ norm_d,
                                                   const float* __restrict__ bs,
                                                   float* __restrict__ score) {
  int node = blockIdx.x * 256 + threadIdx.x;
  int b = node >> 11, n = node & (N_ - 1);
  int r0 = row_ptr[b * (N_ + 1) + n], r1 = row_ptr[b * (N_ + 1) + n + 1];
  const int* cs = csr + (size_t)b * E_;
  float a = 0.f;
  for (int e = r0; e < r1; ++e) a += y[b * N_ + cs[e]];
  score[node] = norm_d[node] * a + bs[0];
}

// ---------------- top-k selection per graph; emits compacted indices + tanh weights ----------------
__global__ __launch_bounds__(256) void k_topk(const float* __restrict__ score,
                                              int* __restrict__ idxs,
                                              float* __restrict__ wsel) {
  __shared__ unsigned int keys[N_];
  __shared__ int red[256];
  int b = blockIdx.x, t = threadIdx.x;
  for (int i = t; i < N_; i += 256) {
    unsigned u = __float_as_uint(score[b * N_ + i]);
    keys[i] = (u & 0x80000000u) ? ~u : (u | 0x80000000u);
  }
  __syncthreads();
  unsigned prefix = 0;
  for (int bit = 31; bit >= 0; bit--) {
    unsigned cand = prefix | (1u << bit);
    int c = 0;
    for (int i = t; i < N_; i += 256) c += ((keys[i] >> bit) >= (cand >> bit));
    red[t] = c;
    __syncthreads();
    for (int off = 128; off > 0; off >>= 1) { if (t < off) red[t] += red[t + off]; __syncthreads(); }
    if (red[0] >= K_) prefix = cand;
    __syncthreads();
  }
  unsigned T = prefix;
  int c = 0;
  for (int i = t; i < N_; i += 256) c += (keys[i] > T);
  red[t] = c;
  __syncthreads();
  for (int off = 128; off > 0; off >>= 1) { if (t < off) red[t] += red[t + off]; __syncthreads(); }
  int R = K_ - red[0];
  __syncthreads();
  unsigned kk[8]; int myt = 0;
  for (int j = 0; j < 8; j++) { kk[j] = keys[t * 8 + j]; myt += (kk[j] == T); }
  red[t] = myt;
  __syncthreads();
  for (int off = 1; off < 256; off <<= 1) {
    int x = (t >= off) ? red[t - off] : 0;
    __syncthreads();
    red[t] += x;
    __syncthreads();
  }
  int rank = red[t] - myt;
  bool sb[8]; int csel = 0;
  for (int j = 0; j < 8; j++) {
    bool tie = (kk[j] == T);
    bool sel = (kk[j] > T) || (tie && rank < R);
    if (tie) rank++;
    sb[j] = sel; csel += sel;
  }
  __syncthreads();
  red[t] = csel;
  __syncthreads();
  for (int off = 1; off < 256; off <<= 1) {
    int x = (t >= off) ? red[t - off] : 0;
    __syncthreads();
    red[t] += x;
    __syncthreads();
  }
  int pos = red[t] - csel;
  for (int j = 0; j < 8; j++) {
    if (sb[j]) {
      int i = t * 8 + j;
      idxs[b * K_ + pos] = i;
      wsel[b * K_ + pos] = tanhf(score[b * N_ + i]);
      pos++;
    }
  }
}

// ---------------- readout partials over SELECTED rows only ----------------
__global__ __launch_bounds__(384) void k_readout_part(const unsigned short* __restrict__ cr,
                                                      const float* __restrict__ wsel,
                                                      const int* __restrict__ idxs,
                                                      float* __restrict__ psum,
                                                      float* __restrict__ pmax) {
  __shared__ int rows[64];
  __shared__ float wv[64];
  int b = blockIdx.x >> 4, ch = blockIdx.x & 15;
  int f = threadIdx.x;
  if (f < 64) {
    rows[f] = idxs[b * K_ + ch * 64 + f];
    wv[f] = wsel[b * K_ + ch * 64 + f];
  }
  __syncthreads();
  float sum = 0.f, mx = -3.402823466e38f;
  for (int s = 0; s < 64; s++) {
    float v = bf2f(cr[((size_t)(b * N_ + rows[s])) * C_ + f]);
    float x = v * wv[s];
    sum += x; mx = fmaxf(mx, x);
  }
  psum[((size_t)b * 16 + ch) * C_ + f] = sum;
  pmax[((size_t)b * 16 + ch) * C_ + f] = mx;
}

__global__ __launch_bounds__(384) void k_readout_red(const float* __restrict__ psum,
                                                     const float* __restrict__ pmax,
                                                     float* __restrict__ g) {
  int b = blockIdx.x, f = threadIdx.x;
  float s = 0.f, m = -3.402823466e38f;
  for (int ch = 0; ch < 16; ch++) {
    s += psum[((size_t)b * 16 + ch) * C_ + f];
    m = fmaxf(m, pmax[((size_t)b * 16 + ch) * C_ + f]);
  }
  g[b * 768 + f] = s * (1.f / K_);
  g[b * 768 + C_ + f] = m;
}

// ---------------- MLP layer 1: h1 = g @ w1 ----------------
__global__ __launch_bounds__(128) void k_mlp1(const float* __restrict__ g,
                                              const float* __restrict__ w1,
                                              float* __restrict__ h1) {
  __shared__ float gr[768];
  int b = blockIdx.x, t = threadIdx.x;
  for (int i = t; i < 768; i += 128) gr[i] = g[b * 768 + i];
  __syncthreads();
  float acc = 0.f;
  for (int k = 0; k < 768; k++) acc += gr[k] * w1[(size_t)k * 128 + t];
  h1[b * 128 + t] = acc;
}

// ---------------- BN + ReLU + mlp_w2 + log_softmax ----------------
__global__ __launch_bounds__(128) void k_mlp2(const float* __restrict__ h1,
                                              const float* __restrict__ bn_g,
                                              const float* __restrict__ bn_b,
                                              const float* __restrict__ w2,
                                              float* __restrict__ out) {
  __shared__ float hn[64][128];
  __shared__ float o[64][10];
  int t = threadIdx.x;   // 128
  float mean = 0.f;
  for (int r = 0; r < 64; r++) mean += h1[r * 128 + t];
  mean *= (1.f / 64.f);
  float var = 0.f;
  for (int r = 0; r < 64; r++) { float d = h1[r * 128 + t] - mean; var += d * d; }
  var *= (1.f / 64.f);
  float sc = bn_g[t] * rsqrtf(var + 1e-5f), sh = bn_b[t];
  for (int r = 0; r < 64; r++) {
    float v = (h1[r * 128 + t] - mean) * sc + sh;
    hn[r][t] = fmaxf(v, 0.f);
  }
  __syncthreads();
  for (int j = 0; j < 5; j++) {
    int idx = t + j * 128;
    int r = idx / 10, c = idx % 10;
    float a = 0.f;
    for (int k = 0; k < 128; k++) a += hn[r][k] * w2[k * 10 + c];
    o[r][c] = a;
  }
  __syncthreads();
  if (t < 64) {
    float mx = -3.402823466e38f;
    for (int c = 0; c < 10; c++) mx = fmaxf(mx, o[t][c]);
    float se = 0.f;
    for (int c = 0; c < 10; c++) se += expf(o[t][c] - mx);
    float l = logf(se);
    for (int c = 0; c < 10; c++) out[t * 10 + c] = o[t][c] - mx - l;
  }
}

extern "C" void kernel_launch(void* const* d_in, const int* in_sizes, int n_in,
                              void* d_out, int out_size, void* d_ws, size_t ws_size,
                              hipStream_t stream) {
  const float* feat = (const float*)d_in[0];
  const int* src = (const int*)d_in[1];
  const int* dst = (const int*)d_in[2];
  const float* W0 = (const float*)d_in[3];  const float* b0 = (const float*)d_in[4];
  const float* W1 = (const float*)d_in[5];  const float* b1 = (const float*)d_in[6];
  const float* W2 = (const float*)d_in[7];  const float* b2 = (const float*)d_in[8];
  const float* Ws = (const float*)d_in[9];  const float* bs = (const float*)d_in[10];
  const float* mw1 = (const float*)d_in[11];
  const float* bng = (const float*)d_in[12];
  const float* bnb = (const float*)d_in[13];
  const float* mw2 = (const float*)d_in[14];
  float* out = (float*)d_out;

  char* p = (char*)d_ws;
  auto alloc = [&](size_t bytes) -> void* {
    void* r = (void*)p;
    p += (bytes + 255) & ~(size_t)255;
    return r;
  };
  int* row_ptr = (int*)alloc((size_t)B_ * (N_ + 1) * 4);
  float* norm_s = (float*)alloc((size_t)NB_ * 4);
  float* norm_d = (float*)alloc((size_t)NB_ * 4);
  int* csr      = (int*)alloc((size_t)B_ * E_ * 4);
  int* order    = (int*)alloc((size_t)NB_ * 4);
  unsigned short* cr  = (unsigned short*)alloc((size_t)NB_ * C_ * 2);
  unsigned short* agg = (unsigned short*)alloc((size_t)NB_ * F_ * 2);
  unsigned short* hsb = (unsigned short*)alloc((size_t)NB_ * F_ * 2);
  float* y     = (float*)alloc((size_t)NB_ * 4);
  float* score = (float*)alloc((size_t)NB_ * 4);
  int* idxs    = (int*)alloc((size_t)B_ * K_ * 4);
  float* wsel  = (float*)alloc((size_t)B_ * K_ * 4);
  float* psum  = (float*)alloc((size_t)B_ * 16 * C_ * 4);
  float* pmax  = (float*)alloc((size_t)B_ * 16 * C_ * 4);
  float* g     = (float*)alloc((size_t)B_ * 768 * 4);
  float* h1    = (float*)alloc((size_t)B_ * 128 * 4);
  unsigned short* wp0h = (unsigned short*)alloc(16384 * 2);
  unsigned short* wp0l = (unsigned short*)alloc(16384 * 2);
  unsigned short* wp1h = (unsigned short*)alloc(16384 * 2);
  unsigned short* wp1l = (unsigned short*)alloc(16384 * 2);
  unsigned short* wp2h = (unsigned short*)alloc(16384 * 2);
  unsigned short* wp2l = (unsigned short*)alloc(16384 * 2);

  // prep: 4 blocks per graph, XCD-pinned so they share one L2
  k_prep<<<dim3(B_ * 4), dim3(1024), 0, stream>>>(src, dst, norm_s, norm_d, row_ptr, csr);
  // per-graph degree sort (descending) -> processing order for k_agg
  k_sort<<<dim3(B_), dim3(256), 0, stream>>>(row_ptr, order);

  // weight packs
  k_packW<<<dim3(8), dim3(256), 0, stream>>>(W0, wp0h, wp0l);
  k_packW<<<dim3(8), dim3(256), 0, stream>>>(W1, wp1h, wp1l);
  k_packW<<<dim3(8), dim3(256), 0, stream>>>(W2, wp2h, wp2l);

  // hs0 = feat * norm_s (bf16), XCD-pinned
  k_f2bf_scaled<<<dim3(NB_ / 16), dim3(256), 0, stream>>>(feat, norm_s, hsb);

  // layer 0
  k_agg<<<dim3(NB_ / 16), dim3(256), 0, stream>>>(hsb, row_ptr, csr, norm_d, order, agg);
  k_gemm_mfma<true><<<dim3(NB_ / 64), dim3(128), 0, stream>>>(agg, wp0h, wp0l, b0, cr, 0,
                                                              norm_s, hsb, Ws, y, 0);
  // layer 1
  k_agg<<<dim3(NB_ / 16), dim3(256), 0, stream>>>(hsb, row_ptr, csr, norm_d, order, agg);
  k_gemm_mfma<true><<<dim3(NB_ / 64), dim3(128), 0, stream>>>(agg, wp1h, wp1l, b1, cr, 128,
                                                              norm_s, hsb, Ws, y, 1);
  // layer 2 (finalize y)
  k_agg<<<dim3(NB_ / 16), dim3(256), 0, stream>>>(hsb, row_ptr, csr, norm_d, order, agg);
  k_gemm_mfma<false><<<dim3(NB_ / 64), dim3(128), 0, stream>>>(agg, wp2h, wp2l, b2, cr, 256,
                                                               norm_s, nullptr, Ws, y, 2);

  // SAGPool score aggregation + top-k (compacted)
  k_score_agg<<<dim3(NB_ / 256), dim3(256), 0, stream>>>(y, row_ptr, csr, norm_d, bs, score);
  k_topk<<<dim3(B_), dim3(256), 0, stream>>>(score, idxs, wsel);

  // readout over selected rows
  k_readout_part<<<dim3(B_ * 16), dim3(384), 0, stream>>>(cr, wsel, idxs, psum, pmax);
  k_readout_red<<<dim3(B_), dim3(384), 0, stream>>>(psum, pmax, g);

  // MLP
  k_mlp1<<<dim3(B_), dim3(128), 0, stream>>>(g, mw1, h1);
  k_mlp2<<<dim3(1), dim3(128), 0, stream>>>(h1, bng, bnb, mw2, out);
}

// Round 19
// 365.490 us; speedup vs baseline: 1.0056x; 1.0056x over previous
//
#include <hip/hip_runtime.h>
#include <hip/hip_bf16.h>
#include <math.h>

#define B_   64
#define N_   2048
#define E_   32768
#define K_   1024
#define F_   128
#define C_   384
#define NB_  (B_ * N_)

typedef __bf16 bf16x8 __attribute__((ext_vector_type(8)));
typedef float  f32x4  __attribute__((ext_vector_type(4)));
typedef float  f32x2  __attribute__((ext_vector_type(2)));

__device__ __forceinline__ float bf2f(unsigned int u) {
  return __uint_as_float(u << 16);   // uses low 16 bits
}
__device__ __forceinline__ unsigned int f2bf(float f) {
  unsigned int x = __float_as_uint(f);
  return (x + 0x7fffu + ((x >> 16) & 1u)) >> 16;   // RNE
}
__device__ __forceinline__ f32x2 bf2x(unsigned int u) {
  f32x2 r;
  r.x = __uint_as_float(u << 16);
  r.y = __uint_as_float(u & 0xffff0000u);
  return r;
}
// LDS staging index: row-major [rows][128] shorts, XOR swizzle at 8-short granules.
__device__ __forceinline__ int swz(int row, int scol) {
  return (row * F_ + scol) ^ ((row & 7) << 3);
}

// ---------------- graph prep: 4 blocks per graph, XCD-pinned (share one L2) ----------------
__global__ __launch_bounds__(1024) void k_prep(const int* __restrict__ src,
                                               const int* __restrict__ dst,
                                               float* __restrict__ norm_s,
                                               float* __restrict__ norm_d,
                                               int* __restrict__ row_ptr,
                                               int* __restrict__ csr) {
  __shared__ int h_in[512];
  __shared__ int h_out[512];
  __shared__ int rowst[512];
  __shared__ int part[512];
  __shared__ int rtot[4];
  int blk = blockIdx.x;
  int b = ((blk >> 5) << 3) | (blk & 7);
  int r = (blk >> 3) & 3;
  int lo = r << 9;
  int t = threadIdx.x;
  if (t < 512) { h_in[t] = 0; h_out[t] = 0; }
  if (t < 4) rtot[t] = 0;
  __syncthreads();
  const int4* sp4 = (const int4*)(src + (size_t)b * E_);
  const int4* dp4 = (const int4*)(dst + (size_t)b * E_);
  int c0 = 0, c1 = 0, c2 = 0, c3 = 0;
  for (int i = t; i < E_ / 4; i += 2048) {
    int4 sA = sp4[i], dA = dp4[i];
    int4 sB = sp4[i + 1024], dB = dp4[i + 1024];
#define EDGE(ss, dd) { int dr = (dd) >> 9; \
    c0 += (dr == 0); c1 += (dr == 1); c2 += (dr == 2); c3 += (dr == 3); \
    if (dr == r) atomicAdd(&h_in[(dd) - lo], 1); \
    if (((ss) >> 9) == r) atomicAdd(&h_out[(ss) - lo], 1); }
    EDGE(sA.x, dA.x); EDGE(sA.y, dA.y); EDGE(sA.z, dA.z); EDGE(sA.w, dA.w);
    EDGE(sB.x, dB.x); EDGE(sB.y, dB.y); EDGE(sB.z, dB.z); EDGE(sB.w, dB.w);
#undef EDGE
  }
  if (c0) atomicAdd(&rtot[0], c0);
  if (c1) atomicAdd(&rtot[1], c1);
  if (c2) atomicAdd(&rtot[2], c2);
  if (c3) atomicAdd(&rtot[3], c3);
  __syncthreads();
  if (t < 512) {
    int dv = h_out[t], di = h_in[t];
    norm_s[b * N_ + lo + t] = dv > 0 ? rsqrtf((float)dv) : 0.f;
    norm_d[b * N_ + lo + t] = di > 0 ? rsqrtf((float)di) : 0.f;
  }
  int base = 0;
  if (r > 0) base += rtot[0];
  if (r > 1) base += rtot[1];
  if (r > 2) base += rtot[2];
  if (t < 512) part[t] = h_in[t];
  __syncthreads();
  for (int off = 1; off < 512; off <<= 1) {
    int x = (t >= off && t < 512) ? part[t - off] : 0;
    __syncthreads();
    if (t < 512) part[t] += x;
    __syncthreads();
  }
  if (t < 512) {
    int st = base + part[t] - h_in[t];
    rowst[t] = st;
    row_ptr[b * (N_ + 1) + lo + t] = st;
    h_in[t] = 0;
  }
  if (r == 3 && t == 511) row_ptr[b * (N_ + 1) + N_] = base + part[511];
  __syncthreads();
  int* cg = csr + (size_t)b * E_;
  for (int i = t; i < E_ / 4; i += 2048) {
    int4 sA = sp4[i], dA = dp4[i];
    int4 sB = sp4[i + 1024], dB = dp4[i + 1024];
#define FILL(ss, dd) if (((dd) >> 9) == r) { \
    int pos = rowst[(dd) - lo] + atomicAdd(&h_in[(dd) - lo], 1); cg[pos] = (ss); }
    FILL(sA.x, dA.x); FILL(sA.y, dA.y); FILL(sA.z, dA.z); FILL(sA.w, dA.w);
    FILL(sB.x, dB.x); FILL(sB.y, dB.y); FILL(sB.z, dB.z); FILL(sB.w, dB.w);
#undef FILL
  }
}

// ---------------- per-graph counting sort of nodes by in-degree (descending) ----------------
__global__ __launch_bounds__(256) void k_sort(const int* __restrict__ row_ptr,
                                              int* __restrict__ order) {
  __shared__ int hist[64];
  __shared__ int base[64];
  int b = blockIdx.x, t = threadIdx.x;
  if (t < 64) hist[t] = 0;
  __syncthreads();
  int degs[8];
  const int* rp = row_ptr + b * (N_ + 1);
  for (int j = 0; j < 8; j++) {
    int n = t * 8 + j;
    int d = rp[n + 1] - rp[n];
    degs[j] = d;
    int bin = 63 - min(d, 63);
    atomicAdd(&hist[bin], 1);
  }
  __syncthreads();
  if (t == 0) {
    int run = 0;
    for (int i = 0; i < 64; i++) { base[i] = run; run += hist[i]; hist[i] = 0; }
  }
  __syncthreads();
  for (int j = 0; j < 8; j++) {
    int n = t * 8 + j;
    int bin = 63 - min(degs[j], 63);
    int pos = base[bin] + atomicAdd(&hist[bin], 1);
    order[b * N_ + pos] = n;
  }
}

// ---------------- feat f32 -> bf16 pre-scaled by norm_s (XCD-pinned per graph) ----------------
__global__ __launch_bounds__(256) void k_f2bf_scaled(const float* __restrict__ in,
                                                     const float* __restrict__ norm_s,
                                                     unsigned short* __restrict__ out) {
  int blk = blockIdx.x;
  int b = ((blk >> 10) << 3) | (blk & 7);
  int nb = (blk >> 3) & 127;
  int t = threadIdx.x;
  int node = b * N_ + nb * 16 + (t >> 4);
  int f0 = (t & 15) * 8;
  float ns = norm_s[node];
  const float4* p = (const float4*)(in + (size_t)node * F_ + f0);
  float4 v0 = p[0], v1 = p[1];
  uint4 o;
  o.x = f2bf(v0.x * ns) | (f2bf(v0.y * ns) << 16);
  o.y = f2bf(v0.z * ns) | (f2bf(v0.w * ns) << 16);
  o.z = f2bf(v1.x * ns) | (f2bf(v1.y * ns) << 16);
  o.w = f2bf(v1.z * ns) | (f2bf(v1.w * ns) << 16);
  *(uint4*)(out + (size_t)node * F_ + f0) = o;
}

// ---------------- aggregate: 16 lanes/node, 16 nodes/block, degree-sorted node order ----------------
__global__ __launch_bounds__(256) void k_agg(const unsigned short* __restrict__ hs,
                                             const int* __restrict__ row_ptr,
                                             const int* __restrict__ csr,
                                             const float* __restrict__ norm_d,
                                             const int* __restrict__ order,
                                             unsigned short* __restrict__ agg) {
  int blk = blockIdx.x;
  int b = ((blk >> 10) << 3) | (blk & 7);
  int nb = (blk >> 3) & 127;
  int t = threadIdx.x;
  int nl = t >> 4, f8 = t & 15;
  int n = order[b * N_ + nb * 16 + nl];
  int node = b * N_ + n;
  int r0 = row_ptr[b * (N_ + 1) + n], r1 = row_ptr[b * (N_ + 1) + n + 1];
  const int* cs = csr + (size_t)b * E_;
  const unsigned short* hb = hs + ((size_t)b * N_) * F_ + f8 * 8;
  f32x2 a01 = {0.f, 0.f}, a23 = {0.f, 0.f}, a45 = {0.f, 0.f}, a67 = {0.f, 0.f};
#define ACC8(u) { a01 += bf2x(u.x); a23 += bf2x(u.y); a45 += bf2x(u.z); a67 += bf2x(u.w); }
  int e = r0;
  for (; e + 8 <= r1; e += 8) {
    int s0 = cs[e],     s1 = cs[e + 1], s2 = cs[e + 2], s3 = cs[e + 3];
    int s4 = cs[e + 4], s5 = cs[e + 5], s6 = cs[e + 6], s7 = cs[e + 7];
    uint4 u0 = *(const uint4*)(hb + (size_t)s0 * F_);
    uint4 u1 = *(const uint4*)(hb + (size_t)s1 * F_);
    uint4 u2 = *(const uint4*)(hb + (size_t)s2 * F_);
    uint4 u3 = *(const uint4*)(hb + (size_t)s3 * F_);
    uint4 u4 = *(const uint4*)(hb + (size_t)s4 * F_);
    uint4 u5 = *(const uint4*)(hb + (size_t)s5 * F_);
    uint4 u6 = *(const uint4*)(hb + (size_t)s6 * F_);
    uint4 u7 = *(const uint4*)(hb + (size_t)s7 * F_);
    ACC8(u0); ACC8(u1); ACC8(u2); ACC8(u3);
    ACC8(u4); ACC8(u5); ACC8(u6); ACC8(u7);
  }
  for (; e < r1; ++e) {
    int s0 = cs[e];
    uint4 u0 = *(const uint4*)(hb + (size_t)s0 * F_);
    ACC8(u0);
  }
#undef ACC8
  float wd = norm_d[node];
  uint4 o;
  o.x = f2bf(a01.x * wd) | (f2bf(a01.y * wd) << 16);
  o.y = f2bf(a23.x * wd) | (f2bf(a23.y * wd) << 16);
  o.z = f2bf(a45.x * wd) | (f2bf(a45.y * wd) << 16);
  o.w = f2bf(a67.x * wd) | (f2bf(a67.y * wd) << 16);
  *(uint4*)(agg + (size_t)node * F_ + f8 * 8) = o;
}

// ---------------- pack W (f32 [128k][128n]) into MFMA fragment layout, bf16 hi/lo ----------------
__global__ __launch_bounds__(256) void k_packW(const float* __restrict__ W,
                                               unsigned short* __restrict__ wp_hi,
                                               unsigned short* __restrict__ wp_lo) {
  int tid = blockIdx.x * 256 + threadIdx.x;
  int lane = tid & 63, frag = tid >> 6;
  if (frag >= 32) return;
  int kt = frag >> 3, nt = frag & 7;
  int k0 = kt * 32 + (lane >> 4) * 8;
  int n = nt * 16 + (lane & 15);
  for (int j = 0; j < 8; j++) {
    float w = W[(size_t)(k0 + j) * 128 + n];
    unsigned int hi = f2bf(w);
    float whi = bf2f(hi);
    unsigned int lo = f2bf(w - whi);
    wp_hi[(size_t)tid * 8 + j] = (unsigned short)hi;
    wp_lo[(size_t)tid * 8 + j] = (unsigned short)lo;
  }
}

// ---------------- MFMA GEMM (transposed) + LDS-staged coalesced epilogue + fused score-y ----------------
// 256 threads (4 waves), 128 nodes/block, grid NB/128, XCD-pinned.
// hs computed from staged cr values during read-back (one extra bf16 rounding).
template <bool WRITE_HS>
__global__ __launch_bounds__(256) void k_gemm_mfma(const unsigned short* __restrict__ agg,
                                                   const unsigned short* __restrict__ wp_hi,
                                                   const unsigned short* __restrict__ wp_lo,
                                                   const float* __restrict__ bias,
                                                   unsigned short* __restrict__ cr,
                                                   int out_off,
                                                   const float* __restrict__ norm_s,
                                                   unsigned short* __restrict__ hs,
                                                   const float* __restrict__ Wsc,
                                                   float* __restrict__ ybuf,
                                                   int ymode) {
  __shared__ unsigned short Stg[128 * F_];       // 32 KB staging
  int blk = blockIdx.x;
  int b = ((blk >> 7) << 3) | (blk & 7);
  int nb = (blk >> 3) & 15;
  int t = threadIdx.x;
  int wave = t >> 6, lane = t & 63;
  int gbase = b * N_ + nb * 128;
  int rl0 = wave * 32;
  int arow = lane & 15, kg = lane >> 4;

  f32x4 acc[2][8];
#pragma unroll
  for (int i = 0; i < 2; i++)
#pragma unroll
    for (int j = 0; j < 8; j++) acc[i][j] = (f32x4){0.f, 0.f, 0.f, 0.f};

#pragma unroll
  for (int kt = 0; kt < 4; ++kt) {
    bf16x8 a0 = *(const bf16x8*)(agg + (size_t)(gbase + rl0 + arow) * F_ + kt * 32 + kg * 8);
    bf16x8 a1 = *(const bf16x8*)(agg + (size_t)(gbase + rl0 + 16 + arow) * F_ + kt * 32 + kg * 8);
    const unsigned short* bh = wp_hi + ((size_t)(kt * 8) * 64 + lane) * 8;
    const unsigned short* bl = wp_lo + ((size_t)(kt * 8) * 64 + lane) * 8;
#pragma unroll
    for (int nt = 0; nt < 8; ++nt) {
      bf16x8 bhv = *(const bf16x8*)(bh + (size_t)nt * 64 * 8);
      bf16x8 blv = *(const bf16x8*)(bl + (size_t)nt * 64 * 8);
      acc[0][nt] = __builtin_amdgcn_mfma_f32_16x16x32_bf16(bhv, a0, acc[0][nt], 0, 0, 0);
      acc[0][nt] = __builtin_amdgcn_mfma_f32_16x16x32_bf16(blv, a0, acc[0][nt], 0, 0, 0);
      acc[1][nt] = __builtin_amdgcn_mfma_f32_16x16x32_bf16(bhv, a1, acc[1][nt], 0, 0, 0);
      acc[1][nt] = __builtin_amdgcn_mfma_f32_16x16x32_bf16(blv, a1, acc[1][nt], 0, 0, 0);
    }
  }

  int fb = kg * 4;
  int l0 = rl0 + arow, l1 = rl0 + 16 + arow;
  float yp0 = 0.f, yp1 = 0.f;
#pragma unroll
  for (int nt = 0; nt < 8; ++nt) {
    float4 bv = *(const float4*)(bias + nt * 16 + fb);
    acc[0][nt][0] += bv.x; acc[0][nt][1] += bv.y; acc[0][nt][2] += bv.z; acc[0][nt][3] += bv.w;
    acc[1][nt][0] += bv.x; acc[1][nt][1] += bv.y; acc[1][nt][2] += bv.z; acc[1][nt][3] += bv.w;
    uint2 p0, p1;
    p0.x = f2bf(acc[0][nt][0]) | (f2bf(acc[0][nt][1]) << 16);
    p0.y = f2bf(acc[0][nt][2]) | (f2bf(acc[0][nt][3]) << 16);
    p1.x = f2bf(acc[1][nt][0]) | (f2bf(acc[1][nt][1]) << 16);
    p1.y = f2bf(acc[1][nt][2]) | (f2bf(acc[1][nt][3]) << 16);
    *(uint2*)&Stg[swz(l0, nt * 16 + fb)] = p0;
    *(uint2*)&Stg[swz(l1, nt * 16 + fb)] = p1;
    float4 wv = *(const float4*)(Wsc + out_off + nt * 16 + fb);
    yp0 += bf2f(p0.x) * wv.x + bf2f(p0.x >> 16) * wv.y + bf2f(p0.y) * wv.z + bf2f(p0.y >> 16) * wv.w;
    yp1 += bf2f(p1.x) * wv.x + bf2f(p1.x >> 16) * wv.y + bf2f(p1.y) * wv.z + bf2f(p1.y >> 16) * wv.w;
  }
  yp0 += __shfl_xor(yp0, 16); yp0 += __shfl_xor(yp0, 32);
  yp1 += __shfl_xor(yp1, 16); yp1 += __shfl_xor(yp1, 32);
  if (kg == 0) {
    int n0 = gbase + l0, n1 = gbase + l1;
    if (ymode == 0)      { ybuf[n0] = yp0; ybuf[n1] = yp1; }
    else if (ymode == 1) { ybuf[n0] += yp0; ybuf[n1] += yp1; }
    else                 { ybuf[n0] = (ybuf[n0] + yp0) * norm_s[n0];
                           ybuf[n1] = (ybuf[n1] + yp1) * norm_s[n1]; }
  }

  // coalesced read-back: cr store + (optional) hs computed on the fly
  int rrow = lane >> 4, chunk = lane & 15;
#pragma unroll
  for (int it = 0; it < 8; ++it) {
    int rl = rl0 + it * 4 + rrow;
    uint4 vv = *(const uint4*)&Stg[swz(rl, chunk * 8)];
    *(uint4*)(cr + (size_t)(gbase + rl) * C_ + out_off + chunk * 8) = vv;
    if (WRITE_HS) {
      float ns = norm_s[gbase + rl];
      uint4 q;
      q.x = f2bf(bf2f(vv.x) * ns) | (f2bf(bf2f(vv.x >> 16) * ns) << 16);
      q.y = f2bf(bf2f(vv.y) * ns) | (f2bf(bf2f(vv.y >> 16) * ns) << 16);
      q.z = f2bf(bf2f(vv.z) * ns) | (f2bf(bf2f(vv.z >> 16) * ns) << 16);
      q.w = f2bf(bf2f(vv.w) * ns) | (f2bf(bf2f(vv.w >> 16) * ns) << 16);
      *(uint4*)(hs + (size_t)(gbase + rl) * F_ + chunk * 8) = q;
    }
  }
}

// ---------------- score stage 2: score[n] = norm_d[n] * sum_in y[src] + bs ----------------
__global__ __launch_bounds__(256) void k_score_agg(const float* __restrict__ y,
                                                   const int* __restrict__ row_ptr,
                                                   const int* __restrict__ csr,
                                                   const float* __restrict__ norm_d,
                                                   const float* __restrict__ bs,
                                                   float* __restrict__ score) {
  int node = blockIdx.x * 256 + threadIdx.x;
  int b = node >> 11, n = node & (N_ - 1);
  int r0 = row_ptr[b * (N_ + 1) + n], r1 = row_ptr[b * (N_ + 1) + n + 1];
  const int* cs = csr + (size_t)b * E_;
  float a = 0.f;
  for (int e = r0; e < r1; ++e) a += y[b * N_ + cs[e]];
  score[node] = norm_d[node] * a + bs[0];
}

// ---------------- top-k selection per graph; emits compacted indices + tanh weights ----------------
__global__ __launch_bounds__(256) void k_topk(const float* __restrict__ score,
                                              int* __restrict__ idxs,
                                              float* __restrict__ wsel) {
  __shared__ unsigned int keys[N_];
  __shared__ int red[256];
  int b = blockIdx.x, t = threadIdx.x;
  for (int i = t; i < N_; i += 256) {
    unsigned u = __float_as_uint(score[b * N_ + i]);
    keys[i] = (u & 0x80000000u) ? ~u : (u | 0x80000000u);
  }
  __syncthreads();
  unsigned prefix = 0;
  for (int bit = 31; bit >= 0; bit--) {
    unsigned cand = prefix | (1u << bit);
    int c = 0;
    for (int i = t; i < N_; i += 256) c += ((keys[i] >> bit) >= (cand >> bit));
    red[t] = c;
    __syncthreads();
    for (int off = 128; off > 0; off >>= 1) { if (t < off) red[t] += red[t + off]; __syncthreads(); }
    if (red[0] >= K_) prefix = cand;
    __syncthreads();
  }
  unsigned T = prefix;
  int c = 0;
  for (int i = t; i < N_; i += 256) c += (keys[i] > T);
  red[t] = c;
  __syncthreads();
  for (int off = 128; off > 0; off >>= 1) { if (t < off) red[t] += red[t + off]; __syncthreads(); }
  int R = K_ - red[0];
  __syncthreads();
  unsigned kk[8]; int myt = 0;
  for (int j = 0; j < 8; j++) { kk[j] = keys[t * 8 + j]; myt += (kk[j] == T); }
  red[t] = myt;
  __syncthreads();
  for (int off = 1; off < 256; off <<= 1) {
    int x = (t >= off) ? red[t - off] : 0;
    __syncthreads();
    red[t] += x;
    __syncthreads();
  }
  int rank = red[t] - myt;
  bool sb[8]; int csel = 0;
  for (int j = 0; j < 8; j++) {
    bool tie = (kk[j] == T);
    bool sel = (kk[j] > T) || (tie && rank < R);
    if (tie) rank++;
    sb[j] = sel; csel += sel;
  }
  __syncthreads();
  red[t] = csel;
  __syncthreads();
  for (int off = 1; off < 256; off <<= 1) {
    int x = (t >= off) ? red[t - off] : 0;
    __syncthreads();
    red[t] += x;
    __syncthreads();
  }
  int pos = red[t] - csel;
  for (int j = 0; j < 8; j++) {
    if (sb[j]) {
      int i = t * 8 + j;
      idxs[b * K_ + pos] = i;
      wsel[b * K_ + pos] = tanhf(score[b * N_ + i]);
      pos++;
    }
  }
}

// ---------------- readout partials over SELECTED rows only ----------------
__global__ __launch_bounds__(384) void k_readout_part(const unsigned short* __restrict__ cr,
                                                      const float* __restrict__ wsel,
                                                      const int* __restrict__ idxs,
                                                      float* __restrict__ psum,
                                                      float* __restrict__ pmax) {
  __shared__ int rows[64];
  __shared__ float wv[64];
  int b = blockIdx.x >> 4, ch = blockIdx.x & 15;
  int f = threadIdx.x;
  if (f < 64) {
    rows[f] = idxs[b * K_ + ch * 64 + f];
    wv[f] = wsel[b * K_ + ch * 64 + f];
  }
  __syncthreads();
  float sum = 0.f, mx = -3.402823466e38f;
  for (int s = 0; s < 64; s++) {
    float v = bf2f(cr[((size_t)(b * N_ + rows[s])) * C_ + f]);
    float x = v * wv[s];
    sum += x; mx = fmaxf(mx, x);
  }
  psum[((size_t)b * 16 + ch) * C_ + f] = sum;
  pmax[((size_t)b * 16 + ch) * C_ + f] = mx;
}

__global__ __launch_bounds__(384) void k_readout_red(const float* __restrict__ psum,
                                                     const float* __restrict__ pmax,
                                                     float* __restrict__ g) {
  int b = blockIdx.x, f = threadIdx.x;
  float s = 0.f, m = -3.402823466e38f;
  for (int ch = 0; ch < 16; ch++) {
    s += psum[((size_t)b * 16 + ch) * C_ + f];
    m = fmaxf(m, pmax[((size_t)b * 16 + ch) * C_ + f]);
  }
  g[b * 768 + f] = s * (1.f / K_);
  g[b * 768 + C_ + f] = m;
}

// ---------------- MLP layer 1: h1 = g @ w1 ----------------
__global__ __launch_bounds__(128) void k_mlp1(const float* __restrict__ g,
                                              const float* __restrict__ w1,
                                              float* __restrict__ h1) {
  __shared__ float gr[768];
  int b = blockIdx.x, t = threadIdx.x;
  for (int i = t; i < 768; i += 128) gr[i] = g[b * 768 + i];
  __syncthreads();
  float acc = 0.f;
  for (int k = 0; k < 768; k++) acc += gr[k] * w1[(size_t)k * 128 + t];
  h1[b * 128 + t] = acc;
}

// ---------------- BN + ReLU + mlp_w2 + log_softmax ----------------
__global__ __launch_bounds__(128) void k_mlp2(const float* __restrict__ h1,
                                              const float* __restrict__ bn_g,
                                              const float* __restrict__ bn_b,
                                              const float* __restrict__ w2,
                                              float* __restrict__ out) {
  __shared__ float hn[64][128];
  __shared__ float o[64][10];
  int t = threadIdx.x;   // 128
  float mean = 0.f;
  for (int r = 0; r < 64; r++) mean += h1[r * 128 + t];
  mean *= (1.f / 64.f);
  float var = 0.f;
  for (int r = 0; r < 64; r++) { float d = h1[r * 128 + t] - mean; var += d * d; }
  var *= (1.f / 64.f);
  float sc = bn_g[t] * rsqrtf(var + 1e-5f), sh = bn_b[t];
  for (int r = 0; r < 64; r++) {
    float v = (h1[r * 128 + t] - mean) * sc + sh;
    hn[r][t] = fmaxf(v, 0.f);
  }
  __syncthreads();
  for (int j = 0; j < 5; j++) {
    int idx = t + j * 128;
    int r = idx / 10, c = idx % 10;
    float a = 0.f;
    for (int k = 0; k < 128; k++) a += hn[r][k] * w2[k * 10 + c];
    o[r][c] = a;
  }
  __syncthreads();
  if (t < 64) {
    float mx = -3.402823466e38f;
    for (int c = 0; c < 10; c++) mx = fmaxf(mx, o[t][c]);
    float se = 0.f;
    for (int c = 0; c < 10; c++) se += expf(o[t][c] - mx);
    float l = logf(se);
    for (int c = 0; c < 10; c++) out[t * 10 + c] = o[t][c] - mx - l;
  }
}

extern "C" void kernel_launch(void* const* d_in, const int* in_sizes, int n_in,
                              void* d_out, int out_size, void* d_ws, size_t ws_size,
                              hipStream_t stream) {
  const float* feat = (const float*)d_in[0];
  const int* src = (const int*)d_in[1];
  const int* dst = (const int*)d_in[2];
  const float* W0 = (const float*)d_in[3];  const float* b0 = (const float*)d_in[4];
  const float* W1 = (const float*)d_in[5];  const float* b1 = (const float*)d_in[6];
  const float* W2 = (const float*)d_in[7];  const float* b2 = (const float*)d_in[8];
  const float* Ws = (const float*)d_in[9];  const float* bs = (const float*)d_in[10];
  const float* mw1 = (const float*)d_in[11];
  const float* bng = (const float*)d_in[12];
  const float* bnb = (const float*)d_in[13];
  const float* mw2 = (const float*)d_in[14];
  float* out = (float*)d_out;

  char* p = (char*)d_ws;
  auto alloc = [&](size_t bytes) -> void* {
    void* r = (void*)p;
    p += (bytes + 255) & ~(size_t)255;
    return r;
  };
  int* row_ptr = (int*)alloc((size_t)B_ * (N_ + 1) * 4);
  float* norm_s = (float*)alloc((size_t)NB_ * 4);
  float* norm_d = (float*)alloc((size_t)NB_ * 4);
  int* csr      = (int*)alloc((size_t)B_ * E_ * 4);
  int* order    = (int*)alloc((size_t)NB_ * 4);
  unsigned short* cr  = (unsigned short*)alloc((size_t)NB_ * C_ * 2);
  unsigned short* agg = (unsigned short*)alloc((size_t)NB_ * F_ * 2);
  unsigned short* hsb = (unsigned short*)alloc((size_t)NB_ * F_ * 2);
  float* y     = (float*)alloc((size_t)NB_ * 4);
  float* score = (float*)alloc((size_t)NB_ * 4);
  int* idxs    = (int*)alloc((size_t)B_ * K_ * 4);
  float* wsel  = (float*)alloc((size_t)B_ * K_ * 4);
  float* psum  = (float*)alloc((size_t)B_ * 16 * C_ * 4);
  float* pmax  = (float*)alloc((size_t)B_ * 16 * C_ * 4);
  float* g     = (float*)alloc((size_t)B_ * 768 * 4);
  float* h1    = (float*)alloc((size_t)B_ * 128 * 4);
  unsigned short* wp0h = (unsigned short*)alloc(16384 * 2);
  unsigned short* wp0l = (unsigned short*)alloc(16384 * 2);
  unsigned short* wp1h = (unsigned short*)alloc(16384 * 2);
  unsigned short* wp1l = (unsigned short*)alloc(16384 * 2);
  unsigned short* wp2h = (unsigned short*)alloc(16384 * 2);
  unsigned short* wp2l = (unsigned short*)alloc(16384 * 2);

  // prep: 4 blocks per graph, XCD-pinned so they share one L2
  k_prep<<<dim3(B_ * 4), dim3(1024), 0, stream>>>(src, dst, norm_s, norm_d, row_ptr, csr);
  // per-graph degree sort (descending) -> processing order for k_agg
  k_sort<<<dim3(B_), dim3(256), 0, stream>>>(row_ptr, order);

  // weight packs
  k_packW<<<dim3(8), dim3(256), 0, stream>>>(W0, wp0h, wp0l);
  k_packW<<<dim3(8), dim3(256), 0, stream>>>(W1, wp1h, wp1l);
  k_packW<<<dim3(8), dim3(256), 0, stream>>>(W2, wp2h, wp2l);

  // hs0 = feat * norm_s (bf16), XCD-pinned
  k_f2bf_scaled<<<dim3(NB_ / 16), dim3(256), 0, stream>>>(feat, norm_s, hsb);

  // layer 0
  k_agg<<<dim3(NB_ / 16), dim3(256), 0, stream>>>(hsb, row_ptr, csr, norm_d, order, agg);
  k_gemm_mfma<true><<<dim3(NB_ / 128), dim3(256), 0, stream>>>(agg, wp0h, wp0l, b0, cr, 0,
                                                               norm_s, hsb, Ws, y, 0);
  // layer 1
  k_agg<<<dim3(NB_ / 16), dim3(256), 0, stream>>>(hsb, row_ptr, csr, norm_d, order, agg);
  k_gemm_mfma<true><<<dim3(NB_ / 128), dim3(256), 0, stream>>>(agg, wp1h, wp1l, b1, cr, 128,
                                                               norm_s, hsb, Ws, y, 1);
  // layer 2 (finalize y)
  k_agg<<<dim3(NB_ / 16), dim3(256), 0, stream>>>(hsb, row_ptr, csr, norm_d, order, agg);
  k_gemm_mfma<false><<<dim3(NB_ / 128), dim3(256), 0, stream>>>(agg, wp2h, wp2l, b2, cr, 256,
                                                                norm_s, nullptr, Ws, y, 2);

  // SAGPool score aggregation + top-k (compacted)
  k_score_agg<<<dim3(NB_ / 256), dim3(256), 0, stream>>>(y, row_ptr, csr, norm_d, bs, score);
  k_topk<<<dim3(B_), dim3(256), 0, stream>>>(score, idxs, wsel);

  // readout over selected rows
  k_readout_part<<<dim3(B_ * 16), dim3(384), 0, stream>>>(cr, wsel, idxs, psum, pmax);
  k_readout_red<<<dim3(B_), dim3(384), 0, stream>>>(psum, pmax, g);

  // MLP
  k_mlp1<<<dim3(B_), dim3(128), 0, stream>>>(g, mw1, h1);
  k_mlp2<<<dim3(1), dim3(128), 0, stream>>>(h1, bng, bnb, mw2, out);
}

// Round 20
// 346.402 us; speedup vs baseline: 1.0610x; 1.0551x over previous
//
#include <hip/hip_runtime.h>
#include <hip/hip_bf16.h>
#include <math.h>

#define B_   64
#define N_   2048
#define E_   32768
#define K_   1024
#define F_   128
#define C_   384
#define NB_  (B_ * N_)

typedef __bf16 bf16x8 __attribute__((ext_vector_type(8)));
typedef float  f32x4  __attribute__((ext_vector_type(4)));
typedef float  f32x2  __attribute__((ext_vector_type(2)));

__device__ __forceinline__ float bf2f(unsigned int u) {
  return __uint_as_float(u << 16);   // uses low 16 bits
}
__device__ __forceinline__ unsigned int f2bf(float f) {
  unsigned int x = __float_as_uint(f);
  return (x + 0x7fffu + ((x >> 16) & 1u)) >> 16;   // RNE
}
__device__ __forceinline__ f32x2 bf2x(unsigned int u) {
  f32x2 r;
  r.x = __uint_as_float(u << 16);
  r.y = __uint_as_float(u & 0xffff0000u);
  return r;
}
// LDS staging index: row-major [128][128] shorts, XOR swizzle at 8-short granules.
__device__ __forceinline__ int swz(int row, int scol) {
  return (row * F_ + scol) ^ ((row & 7) << 3);
}

// ---------------- graph prep: 4 blocks per graph, XCD-pinned (share one L2) ----------------
__global__ __launch_bounds__(1024) void k_prep(const int* __restrict__ src,
                                               const int* __restrict__ dst,
                                               float* __restrict__ norm_s,
                                               float* __restrict__ norm_d,
                                               int* __restrict__ row_ptr,
                                               int* __restrict__ csr) {
  __shared__ int h_in[512];
  __shared__ int h_out[512];
  __shared__ int rowst[512];
  __shared__ int part[512];
  __shared__ int rtot[4];
  int blk = blockIdx.x;
  int b = ((blk >> 5) << 3) | (blk & 7);
  int r = (blk >> 3) & 3;
  int lo = r << 9;
  int t = threadIdx.x;
  if (t < 512) { h_in[t] = 0; h_out[t] = 0; }
  if (t < 4) rtot[t] = 0;
  __syncthreads();
  const int4* sp4 = (const int4*)(src + (size_t)b * E_);
  const int4* dp4 = (const int4*)(dst + (size_t)b * E_);
  int c0 = 0, c1 = 0, c2 = 0, c3 = 0;
  for (int i = t; i < E_ / 4; i += 2048) {
    int4 sA = sp4[i], dA = dp4[i];
    int4 sB = sp4[i + 1024], dB = dp4[i + 1024];
#define EDGE(ss, dd) { int dr = (dd) >> 9; \
    c0 += (dr == 0); c1 += (dr == 1); c2 += (dr == 2); c3 += (dr == 3); \
    if (dr == r) atomicAdd(&h_in[(dd) - lo], 1); \
    if (((ss) >> 9) == r) atomicAdd(&h_out[(ss) - lo], 1); }
    EDGE(sA.x, dA.x); EDGE(sA.y, dA.y); EDGE(sA.z, dA.z); EDGE(sA.w, dA.w);
    EDGE(sB.x, dB.x); EDGE(sB.y, dB.y); EDGE(sB.z, dB.z); EDGE(sB.w, dB.w);
#undef EDGE
  }
  if (c0) atomicAdd(&rtot[0], c0);
  if (c1) atomicAdd(&rtot[1], c1);
  if (c2) atomicAdd(&rtot[2], c2);
  if (c3) atomicAdd(&rtot[3], c3);
  __syncthreads();
  if (t < 512) {
    int dv = h_out[t], di = h_in[t];
    norm_s[b * N_ + lo + t] = dv > 0 ? rsqrtf((float)dv) : 0.f;
    norm_d[b * N_ + lo + t] = di > 0 ? rsqrtf((float)di) : 0.f;
  }
  int base = 0;
  if (r > 0) base += rtot[0];
  if (r > 1) base += rtot[1];
  if (r > 2) base += rtot[2];
  if (t < 512) part[t] = h_in[t];
  __syncthreads();
  for (int off = 1; off < 512; off <<= 1) {
    int x = (t >= off && t < 512) ? part[t - off] : 0;
    __syncthreads();
    if (t < 512) part[t] += x;
    __syncthreads();
  }
  if (t < 512) {
    int st = base + part[t] - h_in[t];
    rowst[t] = st;
    row_ptr[b * (N_ + 1) + lo + t] = st;
    h_in[t] = 0;
  }
  if (r == 3 && t == 511) row_ptr[b * (N_ + 1) + N_] = base + part[511];
  __syncthreads();
  int* cg = csr + (size_t)b * E_;
  for (int i = t; i < E_ / 4; i += 2048) {
    int4 sA = sp4[i], dA = dp4[i];
    int4 sB = sp4[i + 1024], dB = dp4[i + 1024];
#define FILL(ss, dd) if (((dd) >> 9) == r) { \
    int pos = rowst[(dd) - lo] + atomicAdd(&h_in[(dd) - lo], 1); cg[pos] = (ss); }
    FILL(sA.x, dA.x); FILL(sA.y, dA.y); FILL(sA.z, dA.z); FILL(sA.w, dA.w);
    FILL(sB.x, dB.x); FILL(sB.y, dB.y); FILL(sB.z, dB.z); FILL(sB.w, dB.w);
#undef FILL
  }
}

// ---------------- per-graph counting sort of nodes by in-degree (descending) ----------------
__global__ __launch_bounds__(256) void k_sort(const int* __restrict__ row_ptr,
                                              int* __restrict__ order) {
  __shared__ int hist[64];
  __shared__ int base[64];
  int b = blockIdx.x, t = threadIdx.x;
  if (t < 64) hist[t] = 0;
  __syncthreads();
  int degs[8];
  const int* rp = row_ptr + b * (N_ + 1);
  for (int j = 0; j < 8; j++) {
    int n = t * 8 + j;
    int d = rp[n + 1] - rp[n];
    degs[j] = d;
    int bin = 63 - min(d, 63);
    atomicAdd(&hist[bin], 1);
  }
  __syncthreads();
  if (t == 0) {
    int run = 0;
    for (int i = 0; i < 64; i++) { base[i] = run; run += hist[i]; hist[i] = 0; }
  }
  __syncthreads();
  for (int j = 0; j < 8; j++) {
    int n = t * 8 + j;
    int bin = 63 - min(degs[j], 63);
    int pos = base[bin] + atomicAdd(&hist[bin], 1);
    order[b * N_ + pos] = n;
  }
}

// ---------------- feat f32 -> bf16 pre-scaled by norm_s (XCD-pinned per graph) ----------------
__global__ __launch_bounds__(256) void k_f2bf_scaled(const float* __restrict__ in,
                                                     const float* __restrict__ norm_s,
                                                     unsigned short* __restrict__ out) {
  int blk = blockIdx.x;
  int b = ((blk >> 10) << 3) | (blk & 7);
  int nb = (blk >> 3) & 127;
  int t = threadIdx.x;
  int node = b * N_ + nb * 16 + (t >> 4);
  int f0 = (t & 15) * 8;
  float ns = norm_s[node];
  const float4* p = (const float4*)(in + (size_t)node * F_ + f0);
  float4 v0 = p[0], v1 = p[1];
  uint4 o;
  o.x = f2bf(v0.x * ns) | (f2bf(v0.y * ns) << 16);
  o.y = f2bf(v0.z * ns) | (f2bf(v0.w * ns) << 16);
  o.z = f2bf(v1.x * ns) | (f2bf(v1.y * ns) << 16);
  o.w = f2bf(v1.z * ns) | (f2bf(v1.w * ns) << 16);
  *(uint4*)(out + (size_t)node * F_ + f0) = o;
}

// ---------------- aggregate: 16 lanes/node, 16 nodes/block, degree-sorted node order ----------------
__global__ __launch_bounds__(256) void k_agg(const unsigned short* __restrict__ hs,
                                             const int* __restrict__ row_ptr,
                                             const int* __restrict__ csr,
                                             const float* __restrict__ norm_d,
                                             const int* __restrict__ order,
                                             unsigned short* __restrict__ agg) {
  int blk = blockIdx.x;
  int b = ((blk >> 10) << 3) | (blk & 7);
  int nb = (blk >> 3) & 127;
  int t = threadIdx.x;
  int nl = t >> 4, f8 = t & 15;
  int n = order[b * N_ + nb * 16 + nl];
  int node = b * N_ + n;
  int r0 = row_ptr[b * (N_ + 1) + n], r1 = row_ptr[b * (N_ + 1) + n + 1];
  const int* cs = csr + (size_t)b * E_;
  const unsigned short* hb = hs + ((size_t)b * N_) * F_ + f8 * 8;
  f32x2 a01 = {0.f, 0.f}, a23 = {0.f, 0.f}, a45 = {0.f, 0.f}, a67 = {0.f, 0.f};
#define ACC8(u) { a01 += bf2x(u.x); a23 += bf2x(u.y); a45 += bf2x(u.z); a67 += bf2x(u.w); }
  int e = r0;
  for (; e + 8 <= r1; e += 8) {
    int s0 = cs[e],     s1 = cs[e + 1], s2 = cs[e + 2], s3 = cs[e + 3];
    int s4 = cs[e + 4], s5 = cs[e + 5], s6 = cs[e + 6], s7 = cs[e + 7];
    uint4 u0 = *(const uint4*)(hb + (size_t)s0 * F_);
    uint4 u1 = *(const uint4*)(hb + (size_t)s1 * F_);
    uint4 u2 = *(const uint4*)(hb + (size_t)s2 * F_);
    uint4 u3 = *(const uint4*)(hb + (size_t)s3 * F_);
    uint4 u4 = *(const uint4*)(hb + (size_t)s4 * F_);
    uint4 u5 = *(const uint4*)(hb + (size_t)s5 * F_);
    uint4 u6 = *(const uint4*)(hb + (size_t)s6 * F_);
    uint4 u7 = *(const uint4*)(hb + (size_t)s7 * F_);
    ACC8(u0); ACC8(u1); ACC8(u2); ACC8(u3);
    ACC8(u4); ACC8(u5); ACC8(u6); ACC8(u7);
  }
  for (; e < r1; ++e) {
    int s0 = cs[e];
    uint4 u0 = *(const uint4*)(hb + (size_t)s0 * F_);
    ACC8(u0);
  }
#undef ACC8
  float wd = norm_d[node];
  uint4 o;
  o.x = f2bf(a01.x * wd) | (f2bf(a01.y * wd) << 16);
  o.y = f2bf(a23.x * wd) | (f2bf(a23.y * wd) << 16);
  o.z = f2bf(a45.x * wd) | (f2bf(a45.y * wd) << 16);
  o.w = f2bf(a67.x * wd) | (f2bf(a67.y * wd) << 16);
  *(uint4*)(agg + (size_t)node * F_ + f8 * 8) = o;
}

// ---------------- pack W (f32 [128k][128n]) into MFMA fragment layout, bf16 hi/lo ----------------
__global__ __launch_bounds__(256) void k_packW(const float* __restrict__ W,
                                               unsigned short* __restrict__ wp_hi,
                                               unsigned short* __restrict__ wp_lo) {
  int tid = blockIdx.x * 256 + threadIdx.x;
  int lane = tid & 63, frag = tid >> 6;
  if (frag >= 32) return;
  int kt = frag >> 3, nt = frag & 7;
  int k0 = kt * 32 + (lane >> 4) * 8;
  int n = nt * 16 + (lane & 15);
  for (int j = 0; j < 8; j++) {
    float w = W[(size_t)(k0 + j) * 128 + n];
    unsigned int hi = f2bf(w);
    float whi = bf2f(hi);
    unsigned int lo = f2bf(w - whi);
    wp_hi[(size_t)tid * 8 + j] = (unsigned short)hi;
    wp_lo[(size_t)tid * 8 + j] = (unsigned short)lo;
  }
}

// ---------------- MFMA GEMM (transposed) + LDS-staged coalesced epilogue + fused score-y ----------------
template <bool WRITE_HS>
__global__ __launch_bounds__(256) void k_gemm_mfma(const unsigned short* __restrict__ agg,
                                                   const unsigned short* __restrict__ wp_hi,
                                                   const unsigned short* __restrict__ wp_lo,
                                                   const float* __restrict__ bias,
                                                   unsigned short* __restrict__ cr,
                                                   int out_off,
                                                   const float* __restrict__ norm_s,
                                                   unsigned short* __restrict__ hs,
                                                   const float* __restrict__ Wsc,
                                                   float* __restrict__ ybuf,
                                                   int ymode) {
  __shared__ unsigned short Stg[128 * F_];
  int blk = blockIdx.x;
  int b = ((blk >> 7) << 3) | (blk & 7);
  int nb = (blk >> 3) & 15;
  int t = threadIdx.x;
  int wave = t >> 6, lane = t & 63;
  int gbase = b * N_ + nb * 128;
  int rl0 = wave * 32;
  int arow = lane & 15, kg = lane >> 4;

  f32x4 acc[2][8];
#pragma unroll
  for (int i = 0; i < 2; i++)
#pragma unroll
    for (int j = 0; j < 8; j++) acc[i][j] = (f32x4){0.f, 0.f, 0.f, 0.f};

#pragma unroll
  for (int kt = 0; kt < 4; ++kt) {
    bf16x8 a0 = *(const bf16x8*)(agg + (size_t)(gbase + rl0 + arow) * F_ + kt * 32 + kg * 8);
    bf16x8 a1 = *(const bf16x8*)(agg + (size_t)(gbase + rl0 + 16 + arow) * F_ + kt * 32 + kg * 8);
    const unsigned short* bh = wp_hi + ((size_t)(kt * 8) * 64 + lane) * 8;
    const unsigned short* bl = wp_lo + ((size_t)(kt * 8) * 64 + lane) * 8;
#pragma unroll
    for (int nt = 0; nt < 8; ++nt) {
      bf16x8 bhv = *(const bf16x8*)(bh + (size_t)nt * 64 * 8);
      bf16x8 blv = *(const bf16x8*)(bl + (size_t)nt * 64 * 8);
      acc[0][nt] = __builtin_amdgcn_mfma_f32_16x16x32_bf16(bhv, a0, acc[0][nt], 0, 0, 0);
      acc[0][nt] = __builtin_amdgcn_mfma_f32_16x16x32_bf16(blv, a0, acc[0][nt], 0, 0, 0);
      acc[1][nt] = __builtin_amdgcn_mfma_f32_16x16x32_bf16(bhv, a1, acc[1][nt], 0, 0, 0);
      acc[1][nt] = __builtin_amdgcn_mfma_f32_16x16x32_bf16(blv, a1, acc[1][nt], 0, 0, 0);
    }
  }

  int fb = kg * 4;
  int l0 = rl0 + arow, l1 = rl0 + 16 + arow;
  float yp0 = 0.f, yp1 = 0.f;
#pragma unroll
  for (int nt = 0; nt < 8; ++nt) {
    float4 bv = *(const float4*)(bias + nt * 16 + fb);
    acc[0][nt][0] += bv.x; acc[0][nt][1] += bv.y; acc[0][nt][2] += bv.z; acc[0][nt][3] += bv.w;
    acc[1][nt][0] += bv.x; acc[1][nt][1] += bv.y; acc[1][nt][2] += bv.z; acc[1][nt][3] += bv.w;
    uint2 p0, p1;
    p0.x = f2bf(acc[0][nt][0]) | (f2bf(acc[0][nt][1]) << 16);
    p0.y = f2bf(acc[0][nt][2]) | (f2bf(acc[0][nt][3]) << 16);
    p1.x = f2bf(acc[1][nt][0]) | (f2bf(acc[1][nt][1]) << 16);
    p1.y = f2bf(acc[1][nt][2]) | (f2bf(acc[1][nt][3]) << 16);
    *(uint2*)&Stg[swz(l0, nt * 16 + fb)] = p0;
    *(uint2*)&Stg[swz(l1, nt * 16 + fb)] = p1;
    float4 wv = *(const float4*)(Wsc + out_off + nt * 16 + fb);
    yp0 += bf2f(p0.x) * wv.x + bf2f(p0.x >> 16) * wv.y + bf2f(p0.y) * wv.z + bf2f(p0.y >> 16) * wv.w;
    yp1 += bf2f(p1.x) * wv.x + bf2f(p1.x >> 16) * wv.y + bf2f(p1.y) * wv.z + bf2f(p1.y >> 16) * wv.w;
  }
  yp0 += __shfl_xor(yp0, 16); yp0 += __shfl_xor(yp0, 32);
  yp1 += __shfl_xor(yp1, 16); yp1 += __shfl_xor(yp1, 32);
  if (kg == 0) {
    int n0 = gbase + l0, n1 = gbase + l1;
    if (ymode == 0)      { ybuf[n0] = yp0; ybuf[n1] = yp1; }
    else if (ymode == 1) { ybuf[n0] += yp0; ybuf[n1] += yp1; }
    else                 { ybuf[n0] = (ybuf[n0] + yp0) * norm_s[n0];
                           ybuf[n1] = (ybuf[n1] + yp1) * norm_s[n1]; }
  }

  // coalesced cr store: own 32 rows, 4 rows x 16 chunks per iteration (256B/row)
  int rrow = lane >> 4, chunk = lane & 15;
#pragma unroll
  for (int it = 0; it < 8; ++it) {
    int rl = rl0 + it * 4 + rrow;
    uint4 vv = *(const uint4*)&Stg[swz(rl, chunk * 8)];
    *(uint4*)(cr + (size_t)(gbase + rl) * C_ + out_off + chunk * 8) = vv;
  }
  if (WRITE_HS) {
    float ns0 = norm_s[gbase + l0];
    float ns1 = norm_s[gbase + l1];
#pragma unroll
    for (int nt = 0; nt < 8; ++nt) {
      uint2 q0, q1;
      q0.x = f2bf(acc[0][nt][0] * ns0) | (f2bf(acc[0][nt][1] * ns0) << 16);
      q0.y = f2bf(acc[0][nt][2] * ns0) | (f2bf(acc[0][nt][3] * ns0) << 16);
      q1.x = f2bf(acc[1][nt][0] * ns1) | (f2bf(acc[1][nt][1] * ns1) << 16);
      q1.y = f2bf(acc[1][nt][2] * ns1) | (f2bf(acc[1][nt][3] * ns1) << 16);
      *(uint2*)&Stg[swz(l0, nt * 16 + fb)] = q0;
      *(uint2*)&Stg[swz(l1, nt * 16 + fb)] = q1;
    }
#pragma unroll
    for (int it = 0; it < 8; ++it) {
      int rl = rl0 + it * 4 + rrow;
      uint4 vv = *(const uint4*)&Stg[swz(rl, chunk * 8)];
      *(uint4*)(hs + (size_t)(gbase + rl) * F_ + chunk * 8) = vv;
    }
  }
}

// ---------------- score stage 2: score[n] = norm_d[n] * sum_in y[src] + bs ----------------
__global__ __launch_bounds__(256) void k_score_agg(const float* __restrict__ y,
                                                   const int* __restrict__ row_ptr,
                                                   const int* __restrict__ csr,
                                                   const float* __restrict__ norm_d,
                                                   const float* __restrict__ bs,
                                                   float* __restrict__ score) {
  int node = blockIdx.x * 256 + threadIdx.x;
  int b = node >> 11, n = node & (N_ - 1);
  int r0 = row_ptr[b * (N_ + 1) + n], r1 = row_ptr[b * (N_ + 1) + n + 1];
  const int* cs = csr + (size_t)b * E_;
  float a = 0.f;
  for (int e = r0; e < r1; ++e) a += y[b * N_ + cs[e]];
  score[node] = norm_d[node] * a + bs[0];
}

// ---------------- top-k selection per graph; emits compacted indices + tanh weights ----------------
__global__ __launch_bounds__(256) void k_topk(const float* __restrict__ score,
                                              int* __restrict__ idxs,
                                              float* __restrict__ wsel) {
  __shared__ unsigned int keys[N_];
  __shared__ int red[256];
  int b = blockIdx.x, t = threadIdx.x;
  for (int i = t; i < N_; i += 256) {
    unsigned u = __float_as_uint(score[b * N_ + i]);
    keys[i] = (u & 0x80000000u) ? ~u : (u | 0x80000000u);
  }
  __syncthreads();
  unsigned prefix = 0;
  for (int bit = 31; bit >= 0; bit--) {
    unsigned cand = prefix | (1u << bit);
    int c = 0;
    for (int i = t; i < N_; i += 256) c += ((keys[i] >> bit) >= (cand >> bit));
    red[t] = c;
    __syncthreads();
    for (int off = 128; off > 0; off >>= 1) { if (t < off) red[t] += red[t + off]; __syncthreads(); }
    if (red[0] >= K_) prefix = cand;
    __syncthreads();
  }
  unsigned T = prefix;
  int c = 0;
  for (int i = t; i < N_; i += 256) c += (keys[i] > T);
  red[t] = c;
  __syncthreads();
  for (int off = 128; off > 0; off >>= 1) { if (t < off) red[t] += red[t + off]; __syncthreads(); }
  int R = K_ - red[0];
  __syncthreads();
  unsigned kk[8]; int myt = 0;
  for (int j = 0; j < 8; j++) { kk[j] = keys[t * 8 + j]; myt += (kk[j] == T); }
  red[t] = myt;
  __syncthreads();
  for (int off = 1; off < 256; off <<= 1) {
    int x = (t >= off) ? red[t - off] : 0;
    __syncthreads();
    red[t] += x;
    __syncthreads();
  }
  int rank = red[t] - myt;
  bool sb[8]; int csel = 0;
  for (int j = 0; j < 8; j++) {
    bool tie = (kk[j] == T);
    bool sel = (kk[j] > T) || (tie && rank < R);
    if (tie) rank++;
    sb[j] = sel; csel += sel;
  }
  __syncthreads();
  red[t] = csel;
  __syncthreads();
  for (int off = 1; off < 256; off <<= 1) {
    int x = (t >= off) ? red[t - off] : 0;
    __syncthreads();
    red[t] += x;
    __syncthreads();
  }
  int pos = red[t] - csel;
  for (int j = 0; j < 8; j++) {
    if (sb[j]) {
      int i = t * 8 + j;
      idxs[b * K_ + pos] = i;
      wsel[b * K_ + pos] = tanhf(score[b * N_ + i]);
      pos++;
    }
  }
}

// ---------------- readout partials over SELECTED rows only ----------------
__global__ __launch_bounds__(384) void k_readout_part(const unsigned short* __restrict__ cr,
                                                      const float* __restrict__ wsel,
                                                      const int* __restrict__ idxs,
                                                      float* __restrict__ psum,
                                                      float* __restrict__ pmax) {
  __shared__ int rows[64];
  __shared__ float wv[64];
  int b = blockIdx.x >> 4, ch = blockIdx.x & 15;
  int f = threadIdx.x;
  if (f < 64) {
    rows[f] = idxs[b * K_ + ch * 64 + f];
    wv[f] = wsel[b * K_ + ch * 64 + f];
  }
  __syncthreads();
  float sum = 0.f, mx = -3.402823466e38f;
  for (int s = 0; s < 64; s++) {
    float v = bf2f(cr[((size_t)(b * N_ + rows[s])) * C_ + f]);
    float x = v * wv[s];
    sum += x; mx = fmaxf(mx, x);
  }
  psum[((size_t)b * 16 + ch) * C_ + f] = sum;
  pmax[((size_t)b * 16 + ch) * C_ + f] = mx;
}

__global__ __launch_bounds__(384) void k_readout_red(const float* __restrict__ psum,
                                                     const float* __restrict__ pmax,
                                                     float* __restrict__ g) {
  int b = blockIdx.x, f = threadIdx.x;
  float s = 0.f, m = -3.402823466e38f;
  for (int ch = 0; ch < 16; ch++) {
    s += psum[((size_t)b * 16 + ch) * C_ + f];
    m = fmaxf(m, pmax[((size_t)b * 16 + ch) * C_ + f]);
  }
  g[b * 768 + f] = s * (1.f / K_);
  g[b * 768 + C_ + f] = m;
}

// ---------------- MLP layer 1: h1 = g @ w1 ----------------
__global__ __launch_bounds__(128) void k_mlp1(const float* __restrict__ g,
                                              const float* __restrict__ w1,
                                              float* __restrict__ h1) {
  __shared__ float gr[768];
  int b = blockIdx.x, t = threadIdx.x;
  for (int i = t; i < 768; i += 128) gr[i] = g[b * 768 + i];
  __syncthreads();
  float acc = 0.f;
  for (int k = 0; k < 768; k++) acc += gr[k] * w1[(size_t)k * 128 + t];
  h1[b * 128 + t] = acc;
}

// ---------------- BN + ReLU + mlp_w2 + log_softmax ----------------
__global__ __launch_bounds__(128) void k_mlp2(const float* __restrict__ h1,
                                              const float* __restrict__ bn_g,
                                              const float* __restrict__ bn_b,
                                              const float* __restrict__ w2,
                                              float* __restrict__ out) {
  __shared__ float hn[64][128];
  __shared__ float o[64][10];
  int t = threadIdx.x;   // 128
  float mean = 0.f;
  for (int r = 0; r < 64; r++) mean += h1[r * 128 + t];
  mean *= (1.f / 64.f);
  float var = 0.f;
  for (int r = 0; r < 64; r++) { float d = h1[r * 128 + t] - mean; var += d * d; }
  var *= (1.f / 64.f);
  float sc = bn_g[t] * rsqrtf(var + 1e-5f), sh = bn_b[t];
  for (int r = 0; r < 64; r++) {
    float v = (h1[r * 128 + t] - mean) * sc + sh;
    hn[r][t] = fmaxf(v, 0.f);
  }
  __syncthreads();
  for (int j = 0; j < 5; j++) {
    int idx = t + j * 128;
    int r = idx / 10, c = idx % 10;
    float a = 0.f;
    for (int k = 0; k < 128; k++) a += hn[r][k] * w2[k * 10 + c];
    o[r][c] = a;
  }
  __syncthreads();
  if (t < 64) {
    float mx = -3.402823466e38f;
    for (int c = 0; c < 10; c++) mx = fmaxf(mx, o[t][c]);
    float se = 0.f;
    for (int c = 0; c < 10; c++) se += expf(o[t][c] - mx);
    float l = logf(se);
    for (int c = 0; c < 10; c++) out[t * 10 + c] = o[t][c] - mx - l;
  }
}

extern "C" void kernel_launch(void* const* d_in, const int* in_sizes, int n_in,
                              void* d_out, int out_size, void* d_ws, size_t ws_size,
                              hipStream_t stream) {
  const float* feat = (const float*)d_in[0];
  const int* src = (const int*)d_in[1];
  const int* dst = (const int*)d_in[2];
  const float* W0 = (const float*)d_in[3];  const float* b0 = (const float*)d_in[4];
  const float* W1 = (const float*)d_in[5];  const float* b1 = (const float*)d_in[6];
  const float* W2 = (const float*)d_in[7];  const float* b2 = (const float*)d_in[8];
  const float* Ws = (const float*)d_in[9];  const float* bs = (const float*)d_in[10];
  const float* mw1 = (const float*)d_in[11];
  const float* bng = (const float*)d_in[12];
  const float* bnb = (const float*)d_in[13];
  const float* mw2 = (const float*)d_in[14];
  float* out = (float*)d_out;

  char* p = (char*)d_ws;
  auto alloc = [&](size_t bytes) -> void* {
    void* r = (void*)p;
    p += (bytes + 255) & ~(size_t)255;
    return r;
  };
  int* row_ptr = (int*)alloc((size_t)B_ * (N_ + 1) * 4);
  float* norm_s = (float*)alloc((size_t)NB_ * 4);
  float* norm_d = (float*)alloc((size_t)NB_ * 4);
  int* csr      = (int*)alloc((size_t)B_ * E_ * 4);
  int* order    = (int*)alloc((size_t)NB_ * 4);
  unsigned short* cr  = (unsigned short*)alloc((size_t)NB_ * C_ * 2);
  unsigned short* agg = (unsigned short*)alloc((size_t)NB_ * F_ * 2);
  unsigned short* hsb = (unsigned short*)alloc((size_t)NB_ * F_ * 2);
  float* y     = (float*)alloc((size_t)NB_ * 4);
  float* score = (float*)alloc((size_t)NB_ * 4);
  int* idxs    = (int*)alloc((size_t)B_ * K_ * 4);
  float* wsel  = (float*)alloc((size_t)B_ * K_ * 4);
  float* psum  = (float*)alloc((size_t)B_ * 16 * C_ * 4);
  float* pmax  = (float*)alloc((size_t)B_ * 16 * C_ * 4);
  float* g     = (float*)alloc((size_t)B_ * 768 * 4);
  float* h1    = (float*)alloc((size_t)B_ * 128 * 4);
  unsigned short* wp0h = (unsigned short*)alloc(16384 * 2);
  unsigned short* wp0l = (unsigned short*)alloc(16384 * 2);
  unsigned short* wp1h = (unsigned short*)alloc(16384 * 2);
  unsigned short* wp1l = (unsigned short*)alloc(16384 * 2);
  unsigned short* wp2h = (unsigned short*)alloc(16384 * 2);
  unsigned short* wp2l = (unsigned short*)alloc(16384 * 2);

  // prep: 4 blocks per graph, XCD-pinned so they share one L2
  k_prep<<<dim3(B_ * 4), dim3(1024), 0, stream>>>(src, dst, norm_s, norm_d, row_ptr, csr);
  // per-graph degree sort (descending) -> processing order for k_agg
  k_sort<<<dim3(B_), dim3(256), 0, stream>>>(row_ptr, order);

  // weight packs
  k_packW<<<dim3(8), dim3(256), 0, stream>>>(W0, wp0h, wp0l);
  k_packW<<<dim3(8), dim3(256), 0, stream>>>(W1, wp1h, wp1l);
  k_packW<<<dim3(8), dim3(256), 0, stream>>>(W2, wp2h, wp2l);

  // hs0 = feat * norm_s (bf16), XCD-pinned
  k_f2bf_scaled<<<dim3(NB_ / 16), dim3(256), 0, stream>>>(feat, norm_s, hsb);

  // layer 0
  k_agg<<<dim3(NB_ / 16), dim3(256), 0, stream>>>(hsb, row_ptr, csr, norm_d, order, agg);
  k_gemm_mfma<true><<<dim3(NB_ / 128), dim3(256), 0, stream>>>(agg, wp0h, wp0l, b0, cr, 0,
                                                               norm_s, hsb, Ws, y, 0);
  // layer 1
  k_agg<<<dim3(NB_ / 16), dim3(256), 0, stream>>>(hsb, row_ptr, csr, norm_d, order, agg);
  k_gemm_mfma<true><<<dim3(NB_ / 128), dim3(256), 0, stream>>>(agg, wp1h, wp1l, b1, cr, 128,
                                                               norm_s, hsb, Ws, y, 1);
  // layer 2 (finalize y)
  k_agg<<<dim3(NB_ / 16), dim3(256), 0, stream>>>(hsb, row_ptr, csr, norm_d, order, agg);
  k_gemm_mfma<false><<<dim3(NB_ / 128), dim3(256), 0, stream>>>(agg, wp2h, wp2l, b2, cr, 256,
                                                                norm_s, nullptr, Ws, y, 2);

  // SAGPool score aggregation + top-k (compacted)
  k_score_agg<<<dim3(NB_ / 256), dim3(256), 0, stream>>>(y, row_ptr, csr, norm_d, bs, score);
  k_topk<<<dim3(B_), dim3(256), 0, stream>>>(score, idxs, wsel);

  // readout over selected rows
  k_readout_part<<<dim3(B_ * 16), dim3(384), 0, stream>>>(cr, wsel, idxs, psum, pmax);
  k_readout_red<<<dim3(B_), dim3(384), 0, stream>>>(psum, pmax, g);

  // MLP
  k_mlp1<<<dim3(B_), dim3(128), 0, stream>>>(g, mw1, h1);
  k_mlp2<<<dim3(1), dim3(128), 0, stream>>>(h1, bng, bnb, mw2, out);
}